// Round 10
// baseline (94.761 us; speedup 1.0000x reference)
//
#include <hip/hip_runtime.h>
#include <hip/hip_bf16.h>

// MicrotubuleAttention — exact algebraic reduction + bf16 MFMA, single kernel.
//
// GTP penalty: (1 - exp(-gamma*dist))*(-1e9), gamma >= 1e-4 => every
// off-diagonal softmax argument <= -9.9e4 => expf underflows to exactly 0.
// Softmax is exactly one-hot at k==q, so attention output == V_rep and
//   out = (x @ Wv) @ Weff        (4.3 GFLOP total)
// with Weff[c][m] = sum_{r=0..3} Wo[(4*(c>>6)+r)*64 + (c&63)][m]  (GQA fold).
// RoPE/Q/K/polarity are dead code.
//
// ONE persistent kernel (256 blocks == #CUs, co-resident), 3 phases glued by
// a contention-free grid barrier (atomicAdd arrival + read-only acquire-load
// spin; R7's atomicMax-RMW spin was the 40us/barrier bug):
//   0. xb = bf16(x); WvT = bf16(Wv^T); WeffT = bf16(fold(Wo)^T)  (grid-stride,
//      LDS-tile transposes, all R+W coalesced — R9-verified)
//   A. Vb  = xb @ WvT^T    [4096,256]  K=1024   (R9 gemm_xwv, 1 tile/block)
//   B. out = Vb @ WeffT^T  [4096,1024] K=256    (R9 gemm_vb_weff, 2 tiles/blk,
//      LDS-bounce coalesced f32 epilogue)
// GEMM loops: triple-buffered LDS, depth-2 prefetch, counted s_waitcnt vmcnt
// (never 0 mid-loop), one s_barrier per K-step, XCD-chunked swizzle (T1).

using bf16x8 = __attribute__((ext_vector_type(8))) short;
using f32x4  = __attribute__((ext_vector_type(4))) float;

static constexpr int DMODEL = 1024;
static constexpr int KVDIM  = 256;   // H_KV * D_HEAD
static constexpr int ROWS   = 4096;  // B * T
static constexpr int NBLK   = 256;

__device__ inline unsigned short f2bf(float f) {
    __hip_bfloat16 h = __float2bfloat16(f);   // RNE
    return *reinterpret_cast<unsigned short*>(&h);
}

// Grid barrier: one atomicAdd arrival per block, read-only acquire spin.
// __syncthreads() at entry drains every lane's stores (compiler emits
// s_waitcnt vmcnt(0) before s_barrier); __threadfence does L2 wb/inv.
__device__ inline void gbar(unsigned* slot, unsigned target) {
    __syncthreads();
    if (threadIdx.x == 0) {
        __threadfence();
        atomicAdd(slot, 1u);
        while (__hip_atomic_load(slot, __ATOMIC_ACQUIRE,
                                 __HIP_MEMORY_SCOPE_AGENT) < target)
            __builtin_amdgcn_s_sleep(2);
        __threadfence();
    }
    __syncthreads();
}

__global__ __launch_bounds__(256, 2) void fused_kernel(
    const float* __restrict__ x,
    const float* __restrict__ Wv,
    const float* __restrict__ Wo,
    unsigned short* __restrict__ xb,
    unsigned short* __restrict__ WvT,
    unsigned short* __restrict__ WeffT,
    unsigned short* __restrict__ Vb,
    float* __restrict__ out,
    unsigned* __restrict__ bar)
{
    __shared__ __align__(16) char smem[73728];   // 72 KB, phase-shared
    const int bid  = blockIdx.x;
    const int tid  = threadIdx.x;
    const int lane = tid & 63;
    const int w    = tid >> 6;
    const int wr   = w >> 1;
    const int wc   = w & 1;
    const int lr   = lane & 15;
    const int kg   = (lane >> 4) * 8;
    const int rg   = (lane >> 4) * 4;
    const int lrow8 = lane >> 3;
    const int lkoff = (lane & 7) * 8;

    // ================= phase 0: prep (grid-stride, R9 patterns) ==========
    {
        float (*ld)[65] = (float(*)[65])smem;     // 64x65 f32 = 16.6 KB
        for (int job = bid; job < 4224; job += NBLK) {
            __syncthreads();                      // WAR on ld between jobs
            if (job < 4096) {
                // xb = bf16(x), coalesced float4 -> ushort4
                int i = job * 256 + tid;
                float4 v = reinterpret_cast<const float4*>(x)[i];
                ushort4 o;
                o.x = f2bf(v.x); o.y = f2bf(v.y);
                o.z = f2bf(v.z); o.w = f2bf(v.w);
                reinterpret_cast<ushort4*>(xb)[i] = o;
            } else if (job < 4160) {
                // WvT[c][d] = bf16(Wv[d][c]) via 64x64 LDS transpose
                const int tile = job - 4096;
                const int d0 = (tile & 15) * 64;
                const int c0 = (tile >> 4) * 64;
                #pragma unroll
                for (int i = 0; i < 4; ++i) {
                    int row  = i * 16 + (tid >> 4);
                    int col4 = (tid & 15) * 4;
                    float4 v = *reinterpret_cast<const float4*>(
                        Wv + (size_t)(d0 + row) * KVDIM + c0 + col4);
                    ld[row][col4 + 0] = v.x; ld[row][col4 + 1] = v.y;
                    ld[row][col4 + 2] = v.z; ld[row][col4 + 3] = v.w;
                }
                __syncthreads();
                #pragma unroll
                for (int i = 0; i < 4; ++i) {
                    int crow = i * 16 + (tid >> 4);
                    int dcol = (tid & 15) * 4;
                    ushort4 o;
                    o.x = f2bf(ld[dcol + 0][crow]);
                    o.y = f2bf(ld[dcol + 1][crow]);
                    o.z = f2bf(ld[dcol + 2][crow]);
                    o.w = f2bf(ld[dcol + 3][crow]);
                    *reinterpret_cast<ushort4*>(
                        WvT + (size_t)(c0 + crow) * DMODEL + d0 + dcol) = o;
                }
            } else {
                // WeffT[m][c] = bf16(fold(Wo)) via 64(m)x64(c) LDS tile
                const int tile = job - 4160;
                const int m0 = (tile & 15) * 64;
                const int c0 = (tile >> 4) * 64;
                #pragma unroll
                for (int g = 0; g < 16; ++g) {
                    int cl = g * 4 + (tid >> 6);
                    int ml = tid & 63;
                    int c  = c0 + cl;
                    const float* bp = Wo
                        + (size_t)((c >> 6) * 256 + (c & 63)) * DMODEL + m0 + ml;
                    float s = bp[0] + bp[(size_t)64 * DMODEL]
                            + bp[(size_t)128 * DMODEL]
                            + bp[(size_t)192 * DMODEL];
                    ld[cl][ml] = s;
                }
                __syncthreads();
                const int mrow = tid >> 2;
                const int cch  = (tid & 3) * 16;
                #pragma unroll
                for (int jj = 0; jj < 4; ++jj) {
                    ushort4 o;
                    o.x = f2bf(ld[cch + jj * 4 + 0][mrow]);
                    o.y = f2bf(ld[cch + jj * 4 + 1][mrow]);
                    o.z = f2bf(ld[cch + jj * 4 + 2][mrow]);
                    o.w = f2bf(ld[cch + jj * 4 + 3][mrow]);
                    *reinterpret_cast<ushort4*>(
                        WeffT + (size_t)(m0 + mrow) * KVDIM
                              + c0 + cch + jj * 4) = o;
                }
            }
        }
    }
    gbar(bar + 0, NBLK);

    // ================= phase A: Vb = xb @ WvT^T (R9 gemm_xwv) ============
    {
        short* As = (short*)smem;             // 3 x 4096 shorts = 24 KB
        short* Bs = (short*)(smem + 24576);   // 3 x 4096 shorts = 24 KB
        const int swz  = (bid & 7) * 32 + (bid >> 3);
        const int brow = (swz >> 2) * 64;
        const int bcol = (swz & 3) * 64;

        auto stage = [&](int buf, int kt) {
            #pragma unroll
            for (int i = 0; i < 2; ++i) {
                const int ch = w * 2 + i;                   // 0..7
                const unsigned short* g =
                    xb + (size_t)(brow + ch * 8 + lrow8) * DMODEL + kt + lkoff;
                __builtin_amdgcn_global_load_lds(
                    (const __attribute__((address_space(1))) void*)g,
                    (__attribute__((address_space(3))) void*)
                        (As + buf * 4096 + ch * 512),
                    16, 0, 0);
            }
            #pragma unroll
            for (int i = 0; i < 2; ++i) {
                const int ch = w * 2 + i;
                const unsigned short* g =
                    WvT + (size_t)(bcol + ch * 8 + lrow8) * DMODEL + kt + lkoff;
                __builtin_amdgcn_global_load_lds(
                    (const __attribute__((address_space(1))) void*)g,
                    (__attribute__((address_space(3))) void*)
                        (Bs + buf * 4096 + ch * 512),
                    16, 0, 0);
            }
        };

        f32x4 acc[2][2] = {};
        constexpr int nt = DMODEL / 64;       // 16
        stage(0, 0);
        stage(1, 64);
        int bc = 0;
        for (int t = 0; t < nt; ++t) {
            if (t + 1 < nt) asm volatile("s_waitcnt vmcnt(4)" ::: "memory");
            else            asm volatile("s_waitcnt vmcnt(0)" ::: "memory");
            __builtin_amdgcn_s_barrier();

            int bs = bc + 2; if (bs >= 3) bs -= 3;
            if (t + 2 < nt) stage(bs, (t + 2) << 6);

            #pragma unroll
            for (int ks = 0; ks < 2; ++ks) {
                bf16x8 a[2], b[2];
                #pragma unroll
                for (int m = 0; m < 2; ++m)
                    a[m] = *reinterpret_cast<const bf16x8*>(
                        As + bc * 4096
                           + (wr * 32 + m * 16 + lr) * 64 + ks * 32 + kg);
                #pragma unroll
                for (int n = 0; n < 2; ++n)
                    b[n] = *reinterpret_cast<const bf16x8*>(
                        Bs + bc * 4096
                           + (wc * 32 + n * 16 + lr) * 64 + ks * 32 + kg);
                #pragma unroll
                for (int m = 0; m < 2; ++m)
                    #pragma unroll
                    for (int n = 0; n < 2; ++n)
                        acc[m][n] = __builtin_amdgcn_mfma_f32_16x16x32_bf16(
                            a[m], b[n], acc[m][n], 0, 0, 0);
            }
            bc = (bc == 2) ? 0 : bc + 1;
        }
        #pragma unroll
        for (int m = 0; m < 2; ++m)
            #pragma unroll
            for (int n = 0; n < 2; ++n)
                #pragma unroll
                for (int j = 0; j < 4; ++j) {
                    const size_t row = brow + wr * 32 + m * 16 + rg + j;
                    const size_t col = bcol + wc * 32 + n * 16 + lr;
                    Vb[row * KVDIM + col] = f2bf(acc[m][n][j]);
                }
    }
    gbar(bar + 1, NBLK);

    // ================= phase B: out = Vb @ WeffT^T (R9, 2 tiles/block) ====
    {
        short* As = (short*)smem;             // 3 x 8192 shorts = 48 KB
        short* Bs = (short*)(smem + 49152);   // 3 x 4096 shorts = 24 KB

        for (int rep = 0; rep < 2; ++rep) {
            const int vb   = bid * 2 + rep;
            const int swz  = (vb & 7) * 64 + (vb >> 3);
            const int brow = (swz >> 4) * 128;
            const int bcol = (swz & 15) * 64;
            __syncthreads();                  // WAR on LDS between reps

            auto stage = [&](int buf, int kt) {
                #pragma unroll
                for (int i = 0; i < 4; ++i) {
                    const int ch = w * 4 + i;               // 0..15
                    const unsigned short* g =
                        Vb + (size_t)(brow + ch * 8 + lrow8) * KVDIM
                           + kt + lkoff;
                    __builtin_amdgcn_global_load_lds(
                        (const __attribute__((address_space(1))) void*)g,
                        (__attribute__((address_space(3))) void*)
                            (As + buf * 8192 + ch * 512),
                        16, 0, 0);
                }
                #pragma unroll
                for (int i = 0; i < 2; ++i) {
                    const int ch = w * 2 + i;               // 0..7
                    const unsigned short* g =
                        WeffT + (size_t)(bcol + ch * 8 + lrow8) * KVDIM
                              + kt + lkoff;
                    __builtin_amdgcn_global_load_lds(
                        (const __attribute__((address_space(1))) void*)g,
                        (__attribute__((address_space(3))) void*)
                            (Bs + buf * 4096 + ch * 512),
                        16, 0, 0);
                }
            };

            f32x4 acc[4][2] = {};
            constexpr int nt = KVDIM / 64;    // 4
            stage(0, 0);
            stage(1, 64);
            int bc = 0;
            for (int t = 0; t < nt; ++t) {
                if (t + 1 < nt) asm volatile("s_waitcnt vmcnt(6)" ::: "memory");
                else            asm volatile("s_waitcnt vmcnt(0)" ::: "memory");
                __builtin_amdgcn_s_barrier();

                int bs = bc + 2; if (bs >= 3) bs -= 3;
                if (t + 2 < nt) stage(bs, (t + 2) << 6);

                #pragma unroll
                for (int ks = 0; ks < 2; ++ks) {
                    bf16x8 a[4], b[2];
                    #pragma unroll
                    for (int m = 0; m < 4; ++m)
                        a[m] = *reinterpret_cast<const bf16x8*>(
                            As + bc * 8192
                               + (wr * 64 + m * 16 + lr) * 64 + ks * 32 + kg);
                    #pragma unroll
                    for (int n = 0; n < 2; ++n)
                        b[n] = *reinterpret_cast<const bf16x8*>(
                            Bs + bc * 4096
                               + (wc * 32 + n * 16 + lr) * 64 + ks * 32 + kg);
                    #pragma unroll
                    for (int m = 0; m < 4; ++m)
                        #pragma unroll
                        for (int n = 0; n < 2; ++n)
                            acc[m][n] = __builtin_amdgcn_mfma_f32_16x16x32_bf16(
                                a[m], b[n], acc[m][n], 0, 0, 0);
                }
                bc = (bc == 2) ? 0 : bc + 1;
            }

            // Epilogue: acc -> LDS [128][65] f32 -> coalesced float4 stores.
            float* Cl = reinterpret_cast<float*>(As);   // 33.3 KB of 48 KB
            __syncthreads();
            #pragma unroll
            for (int m = 0; m < 4; ++m)
                #pragma unroll
                for (int n = 0; n < 2; ++n)
                    #pragma unroll
                    for (int j = 0; j < 4; ++j)
                        Cl[(wr * 64 + m * 16 + rg + j) * 65
                           + wc * 32 + n * 16 + lr] = acc[m][n][j];
            __syncthreads();
            #pragma unroll
            for (int i = 0; i < 8; ++i) {     // 128x64 f32: 8 float4/thread
                const int idx = i * 256 + tid;
                const int row = idx >> 4;
                const int c4  = (idx & 15) * 4;
                float4 v;
                v.x = Cl[row * 65 + c4 + 0];
                v.y = Cl[row * 65 + c4 + 1];
                v.z = Cl[row * 65 + c4 + 2];
                v.w = Cl[row * 65 + c4 + 3];
                *reinterpret_cast<float4*>(
                    out + (size_t)(brow + row) * DMODEL + bcol + c4) = v;
            }
        }
    }
}

extern "C" void kernel_launch(void* const* d_in, const int* in_sizes, int n_in,
                              void* d_out, int out_size, void* d_ws, size_t ws_size,
                              hipStream_t stream) {
    const float* x  = (const float*)d_in[0];   // (4096, 1024)
    const float* Wv = (const float*)d_in[3];   // (1024, 256)
    const float* Wo = (const float*)d_in[4];   // (1024, 1024)
    float* out = (float*)d_out;                // (4096, 1024) f32

    unsigned short* xb    = (unsigned short*)d_ws;           // 8 MB
    unsigned short* WvT   = xb    + (size_t)ROWS * DMODEL;   // 0.5 MB [c][d]
    unsigned short* WeffT = WvT   + (size_t)KVDIM * DMODEL;  // 0.5 MB [m][c]
    unsigned short* Vb    = WeffT + (size_t)DMODEL * KVDIM;  // 2 MB   [r][c]
    unsigned*       bar   = (unsigned*)(Vb + (size_t)ROWS * KVDIM);

    hipMemsetAsync(bar, 0, 2 * sizeof(unsigned), stream);
    fused_kernel<<<NBLK, 256, 0, stream>>>(
        x, Wv, Wo, xb, WvT, WeffT, Vb, out, bar);
}

// Round 11
// 79.779 us; speedup vs baseline: 1.1878x; 1.1878x over previous
//
#include <hip/hip_runtime.h>
#include <hip/hip_bf16.h>

// MicrotubuleAttention — exact algebraic reduction + bf16 MFMA, single kernel.
//
// GTP penalty: (1 - exp(-gamma*dist))*(-1e9), gamma >= 1e-4 => every
// off-diagonal softmax argument <= -9.9e4 => expf underflows to exactly 0.
// Softmax is exactly one-hot at k==q, so attention output == V_rep and
//   out = (x @ Wv) @ Weff        (4.3 GFLOP total)
// with Weff[c][m] = sum_{r=0..3} Wo[(4*(c>>6)+r)*64 + (c&63)][m]  (GQA fold).
// RoPE/Q/K/polarity are dead code.
//
// ONE persistent kernel (256 blocks == #CUs, co-resident), 3 phases glued by
// a grid barrier. BARRIER FIX vs R10: the spin poll is a RELAXED agent atomic
// load (no per-iteration cache op). R10's ACQUIRE-per-poll emitted buffer_inv
// (full L2 invalidate) every iteration -> thousands of invalidates thrashing
// the L2 under still-working blocks (~38us/barrier). One release fence before
// arrival, one acquire fence after exit — per block per barrier.
//   0. xb = bf16(x); WvT = bf16(Wv^T); WeffT = bf16(fold(Wo)^T)  (grid-stride,
//      LDS-tile transposes, all R+W coalesced — R9-verified)
//   A. Vb  = xb @ WvT^T    [4096,256]  K=1024   (R9 gemm_xwv, 1 tile/block)
//   B. out = Vb @ WeffT^T  [4096,1024] K=256    (R9 gemm_vb_weff, 2 tiles/blk,
//      LDS-bounce coalesced f32 epilogue)
// GEMM loops: triple-buffered LDS, depth-2 prefetch, counted s_waitcnt vmcnt
// (never 0 mid-loop), one s_barrier per K-step, XCD-chunked swizzle (T1).

using bf16x8 = __attribute__((ext_vector_type(8))) short;
using f32x4  = __attribute__((ext_vector_type(4))) float;

static constexpr int DMODEL = 1024;
static constexpr int KVDIM  = 256;   // H_KV * D_HEAD
static constexpr int ROWS   = 4096;  // B * T
static constexpr int NBLK   = 256;

__device__ inline unsigned short f2bf(float f) {
    __hip_bfloat16 h = __float2bfloat16(f);   // RNE
    return *reinterpret_cast<unsigned short*>(&h);
}

// Grid barrier: one atomicAdd arrival per block; RELAXED read-only spin
// (coherence-point load, NO per-iteration fence/invalidate); single
// release fence before arrival and single acquire fence after exit.
__device__ inline void gbar(unsigned* slot, unsigned target) {
    __syncthreads();                 // drains lanes' stores (vmcnt 0)
    if (threadIdx.x == 0) {
        __threadfence();             // release: publish this block's stores
        atomicAdd(slot, 1u);
        while (__hip_atomic_load(slot, __ATOMIC_RELAXED,
                                 __HIP_MEMORY_SCOPE_AGENT) < target)
            __builtin_amdgcn_s_sleep(8);
        __threadfence();             // acquire: one L2 inv per block
    }
    __syncthreads();
}

__global__ __launch_bounds__(256, 2) void fused_kernel(
    const float* __restrict__ x,
    const float* __restrict__ Wv,
    const float* __restrict__ Wo,
    unsigned short* __restrict__ xb,
    unsigned short* __restrict__ WvT,
    unsigned short* __restrict__ WeffT,
    unsigned short* __restrict__ Vb,
    float* __restrict__ out,
    unsigned* __restrict__ bar)
{
    __shared__ __align__(16) char smem[73728];   // 72 KB, phase-shared
    const int bid  = blockIdx.x;
    const int tid  = threadIdx.x;
    const int lane = tid & 63;
    const int w    = tid >> 6;
    const int wr   = w >> 1;
    const int wc   = w & 1;
    const int lr   = lane & 15;
    const int kg   = (lane >> 4) * 8;
    const int rg   = (lane >> 4) * 4;
    const int lrow8 = lane >> 3;
    const int lkoff = (lane & 7) * 8;

    // ================= phase 0: prep (grid-stride, R9 patterns) ==========
    {
        float (*ld)[65] = (float(*)[65])smem;     // 64x65 f32 = 16.6 KB
        for (int job = bid; job < 4224; job += NBLK) {
            if (job < 4096) {
                // xb = bf16(x), coalesced float4 -> ushort4 (no LDS use)
                int i = job * 256 + tid;
                float4 v = reinterpret_cast<const float4*>(x)[i];
                ushort4 o;
                o.x = f2bf(v.x); o.y = f2bf(v.y);
                o.z = f2bf(v.z); o.w = f2bf(v.w);
                reinterpret_cast<ushort4*>(xb)[i] = o;
            } else if (job < 4160) {
                // WvT[c][d] = bf16(Wv[d][c]) via 64x64 LDS transpose
                const int tile = job - 4096;
                const int d0 = (tile & 15) * 64;
                const int c0 = (tile >> 4) * 64;
                #pragma unroll
                for (int i = 0; i < 4; ++i) {
                    int row  = i * 16 + (tid >> 4);
                    int col4 = (tid & 15) * 4;
                    float4 v = *reinterpret_cast<const float4*>(
                        Wv + (size_t)(d0 + row) * KVDIM + c0 + col4);
                    ld[row][col4 + 0] = v.x; ld[row][col4 + 1] = v.y;
                    ld[row][col4 + 2] = v.z; ld[row][col4 + 3] = v.w;
                }
                __syncthreads();
                #pragma unroll
                for (int i = 0; i < 4; ++i) {
                    int crow = i * 16 + (tid >> 4);
                    int dcol = (tid & 15) * 4;
                    ushort4 o;
                    o.x = f2bf(ld[dcol + 0][crow]);
                    o.y = f2bf(ld[dcol + 1][crow]);
                    o.z = f2bf(ld[dcol + 2][crow]);
                    o.w = f2bf(ld[dcol + 3][crow]);
                    *reinterpret_cast<ushort4*>(
                        WvT + (size_t)(c0 + crow) * DMODEL + d0 + dcol) = o;
                }
            } else {
                // WeffT[m][c] = bf16(fold(Wo)) via 64(m)x64(c) LDS tile
                const int tile = job - 4160;
                const int m0 = (tile & 15) * 64;
                const int c0 = (tile >> 4) * 64;
                #pragma unroll
                for (int g = 0; g < 16; ++g) {
                    int cl = g * 4 + (tid >> 6);
                    int ml = tid & 63;
                    int c  = c0 + cl;
                    const float* bp = Wo
                        + (size_t)((c >> 6) * 256 + (c & 63)) * DMODEL + m0 + ml;
                    float s = bp[0] + bp[(size_t)64 * DMODEL]
                            + bp[(size_t)128 * DMODEL]
                            + bp[(size_t)192 * DMODEL];
                    ld[cl][ml] = s;
                }
                __syncthreads();
                const int mrow = tid >> 2;
                const int cch  = (tid & 3) * 16;
                #pragma unroll
                for (int jj = 0; jj < 4; ++jj) {
                    ushort4 o;
                    o.x = f2bf(ld[cch + jj * 4 + 0][mrow]);
                    o.y = f2bf(ld[cch + jj * 4 + 1][mrow]);
                    o.z = f2bf(ld[cch + jj * 4 + 2][mrow]);
                    o.w = f2bf(ld[cch + jj * 4 + 3][mrow]);
                    *reinterpret_cast<ushort4*>(
                        WeffT + (size_t)(m0 + mrow) * KVDIM
                              + c0 + cch + jj * 4) = o;
                }
            }
        }
    }
    gbar(bar + 0, NBLK);

    // ================= phase A: Vb = xb @ WvT^T (R9 gemm_xwv) ============
    {
        short* As = (short*)smem;             // 3 x 4096 shorts = 24 KB
        short* Bs = (short*)(smem + 24576);   // 3 x 4096 shorts = 24 KB
        const int swz  = (bid & 7) * 32 + (bid >> 3);
        const int brow = (swz >> 2) * 64;
        const int bcol = (swz & 3) * 64;

        auto stage = [&](int buf, int kt) {
            #pragma unroll
            for (int i = 0; i < 2; ++i) {
                const int ch = w * 2 + i;                   // 0..7
                const unsigned short* g =
                    xb + (size_t)(brow + ch * 8 + lrow8) * DMODEL + kt + lkoff;
                __builtin_amdgcn_global_load_lds(
                    (const __attribute__((address_space(1))) void*)g,
                    (__attribute__((address_space(3))) void*)
                        (As + buf * 4096 + ch * 512),
                    16, 0, 0);
            }
            #pragma unroll
            for (int i = 0; i < 2; ++i) {
                const int ch = w * 2 + i;
                const unsigned short* g =
                    WvT + (size_t)(bcol + ch * 8 + lrow8) * DMODEL + kt + lkoff;
                __builtin_amdgcn_global_load_lds(
                    (const __attribute__((address_space(1))) void*)g,
                    (__attribute__((address_space(3))) void*)
                        (Bs + buf * 4096 + ch * 512),
                    16, 0, 0);
            }
        };

        f32x4 acc[2][2] = {};
        constexpr int nt = DMODEL / 64;       // 16
        stage(0, 0);
        stage(1, 64);
        int bc = 0;
        for (int t = 0; t < nt; ++t) {
            if (t + 1 < nt) asm volatile("s_waitcnt vmcnt(4)" ::: "memory");
            else            asm volatile("s_waitcnt vmcnt(0)" ::: "memory");
            __builtin_amdgcn_s_barrier();

            int bs = bc + 2; if (bs >= 3) bs -= 3;
            if (t + 2 < nt) stage(bs, (t + 2) << 6);

            #pragma unroll
            for (int ks = 0; ks < 2; ++ks) {
                bf16x8 a[2], b[2];
                #pragma unroll
                for (int m = 0; m < 2; ++m)
                    a[m] = *reinterpret_cast<const bf16x8*>(
                        As + bc * 4096
                           + (wr * 32 + m * 16 + lr) * 64 + ks * 32 + kg);
                #pragma unroll
                for (int n = 0; n < 2; ++n)
                    b[n] = *reinterpret_cast<const bf16x8*>(
                        Bs + bc * 4096
                           + (wc * 32 + n * 16 + lr) * 64 + ks * 32 + kg);
                #pragma unroll
                for (int m = 0; m < 2; ++m)
                    #pragma unroll
                    for (int n = 0; n < 2; ++n)
                        acc[m][n] = __builtin_amdgcn_mfma_f32_16x16x32_bf16(
                            a[m], b[n], acc[m][n], 0, 0, 0);
            }
            bc = (bc == 2) ? 0 : bc + 1;
        }
        #pragma unroll
        for (int m = 0; m < 2; ++m)
            #pragma unroll
            for (int n = 0; n < 2; ++n)
                #pragma unroll
                for (int j = 0; j < 4; ++j) {
                    const size_t row = brow + wr * 32 + m * 16 + rg + j;
                    const size_t col = bcol + wc * 32 + n * 16 + lr;
                    Vb[row * KVDIM + col] = f2bf(acc[m][n][j]);
                }
    }
    gbar(bar + 1, NBLK);

    // ================= phase B: out = Vb @ WeffT^T (R9, 2 tiles/block) ====
    {
        short* As = (short*)smem;             // 3 x 8192 shorts = 48 KB
        short* Bs = (short*)(smem + 49152);   // 3 x 4096 shorts = 24 KB

        for (int rep = 0; rep < 2; ++rep) {
            const int vb   = bid * 2 + rep;
            const int swz  = (vb & 7) * 64 + (vb >> 3);
            const int brow = (swz >> 4) * 128;
            const int bcol = (swz & 15) * 64;
            __syncthreads();                  // WAR on LDS between reps

            auto stage = [&](int buf, int kt) {
                #pragma unroll
                for (int i = 0; i < 4; ++i) {
                    const int ch = w * 4 + i;               // 0..15
                    const unsigned short* g =
                        Vb + (size_t)(brow + ch * 8 + lrow8) * KVDIM
                           + kt + lkoff;
                    __builtin_amdgcn_global_load_lds(
                        (const __attribute__((address_space(1))) void*)g,
                        (__attribute__((address_space(3))) void*)
                            (As + buf * 8192 + ch * 512),
                        16, 0, 0);
                }
                #pragma unroll
                for (int i = 0; i < 2; ++i) {
                    const int ch = w * 2 + i;               // 0..7
                    const unsigned short* g =
                        WeffT + (size_t)(bcol + ch * 8 + lrow8) * KVDIM
                              + kt + lkoff;
                    __builtin_amdgcn_global_load_lds(
                        (const __attribute__((address_space(1))) void*)g,
                        (__attribute__((address_space(3))) void*)
                            (Bs + buf * 4096 + ch * 512),
                        16, 0, 0);
                }
            };

            f32x4 acc[4][2] = {};
            constexpr int nt = KVDIM / 64;    // 4
            stage(0, 0);
            stage(1, 64);
            int bc = 0;
            for (int t = 0; t < nt; ++t) {
                if (t + 1 < nt) asm volatile("s_waitcnt vmcnt(6)" ::: "memory");
                else            asm volatile("s_waitcnt vmcnt(0)" ::: "memory");
                __builtin_amdgcn_s_barrier();

                int bs = bc + 2; if (bs >= 3) bs -= 3;
                if (t + 2 < nt) stage(bs, (t + 2) << 6);

                #pragma unroll
                for (int ks = 0; ks < 2; ++ks) {
                    bf16x8 a[4], b[2];
                    #pragma unroll
                    for (int m = 0; m < 4; ++m)
                        a[m] = *reinterpret_cast<const bf16x8*>(
                            As + bc * 8192
                               + (wr * 64 + m * 16 + lr) * 64 + ks * 32 + kg);
                    #pragma unroll
                    for (int n = 0; n < 2; ++n)
                        b[n] = *reinterpret_cast<const bf16x8*>(
                            Bs + bc * 4096
                               + (wc * 32 + n * 16 + lr) * 64 + ks * 32 + kg);
                    #pragma unroll
                    for (int m = 0; m < 4; ++m)
                        #pragma unroll
                        for (int n = 0; n < 2; ++n)
                            acc[m][n] = __builtin_amdgcn_mfma_f32_16x16x32_bf16(
                                a[m], b[n], acc[m][n], 0, 0, 0);
                }
                bc = (bc == 2) ? 0 : bc + 1;
            }

            // Epilogue: acc -> LDS [128][65] f32 -> coalesced float4 stores.
            float* Cl = reinterpret_cast<float*>(As);   // 33.3 KB of 48 KB
            __syncthreads();
            #pragma unroll
            for (int m = 0; m < 4; ++m)
                #pragma unroll
                for (int n = 0; n < 2; ++n)
                    #pragma unroll
                    for (int j = 0; j < 4; ++j)
                        Cl[(wr * 64 + m * 16 + rg + j) * 65
                           + wc * 32 + n * 16 + lr] = acc[m][n][j];
            __syncthreads();
            #pragma unroll
            for (int i = 0; i < 8; ++i) {     // 128x64 f32: 8 float4/thread
                const int idx = i * 256 + tid;
                const int row = idx >> 4;
                const int c4  = (idx & 15) * 4;
                float4 v;
                v.x = Cl[row * 65 + c4 + 0];
                v.y = Cl[row * 65 + c4 + 1];
                v.z = Cl[row * 65 + c4 + 2];
                v.w = Cl[row * 65 + c4 + 3];
                *reinterpret_cast<float4*>(
                    out + (size_t)(brow + row) * DMODEL + bcol + c4) = v;
            }
        }
    }
}

extern "C" void kernel_launch(void* const* d_in, const int* in_sizes, int n_in,
                              void* d_out, int out_size, void* d_ws, size_t ws_size,
                              hipStream_t stream) {
    const float* x  = (const float*)d_in[0];   // (4096, 1024)
    const float* Wv = (const float*)d_in[3];   // (1024, 256)
    const float* Wo = (const float*)d_in[4];   // (1024, 1024)
    float* out = (float*)d_out;                // (4096, 1024) f32

    unsigned short* xb    = (unsigned short*)d_ws;           // 8 MB
    unsigned short* WvT   = xb    + (size_t)ROWS * DMODEL;   // 0.5 MB [c][d]
    unsigned short* WeffT = WvT   + (size_t)KVDIM * DMODEL;  // 0.5 MB [m][c]
    unsigned short* Vb    = WeffT + (size_t)DMODEL * KVDIM;  // 2 MB   [r][c]
    unsigned*       bar   = (unsigned*)(Vb + (size_t)ROWS * KVDIM);

    hipMemsetAsync(bar, 0, 2 * sizeof(unsigned), stream);
    fused_kernel<<<NBLK, 256, 0, stream>>>(
        x, Wv, Wo, xb, WvT, WeffT, Vb, out, bar);
}

// Round 12
// 45.918 us; speedup vs baseline: 2.0637x; 1.7374x over previous
//
#include <hip/hip_runtime.h>
#include <hip/hip_bf16.h>

// MicrotubuleAttention — exact algebraic reduction + bf16 MFMA.
//
// GTP penalty: (1 - exp(-gamma*dist))*(-1e9), gamma >= 1e-4 => every
// off-diagonal softmax argument <= -9.9e4 => expf underflows to exactly 0.
// Softmax is exactly one-hot at k==q, so attention output == V_rep and
//   out = (x @ Wv) @ Weff        (4.3 GFLOP total)
// with Weff[c][m] = sum_{r=0..3} Wo[(4*(c>>6)+r)*64 + (c&63)][m]  (GQA fold).
// RoPE/Q/K/polarity are dead code.  Pipeline (3 launches):
//   1. prepW: WvT = bf16(Wv^T); WeffT = bf16(fold(Wo)^T)  (weights only,
//             LDS-tile transposes, coalesced R+W — R9-verified)
//   2. Vb    = bf16(x) @ WvT^T   [4096,256] K=1024 — x staged DIRECTLY as
//             f32 via global_load_lds (no xb round trip; saves 16MB HBM);
//             f32->bf16 at fragment read (v_cvt_pk_bf16_f32, off crit path)
//   3. out   = Vb @ WeffT^T      [4096,1024] K=256 (R9 verbatim, LDS-bounce
//             coalesced f32 epilogue)
// GEMM loops (R5/R9-verified): triple-buffered LDS, depth-2 prefetch,
// counted s_waitcnt vmcnt(6) (never 0 mid-loop), ONE s_barrier per K-step,
// XCD-chunked swizzle (T1).

using bf16x8 = __attribute__((ext_vector_type(8))) short;
using f32x4  = __attribute__((ext_vector_type(4))) float;

static constexpr int DMODEL = 1024;
static constexpr int KVDIM  = 256;   // H_KV * D_HEAD
static constexpr int ROWS   = 4096;  // B * T

__device__ inline unsigned short f2bf(float f) {
    __hip_bfloat16 h = __float2bfloat16(f);   // RNE
    return *reinterpret_cast<unsigned short*>(&h);
}

// ---- weights prep: 128 blocks of 64x64 LDS-transpose tiles ---------------
__global__ void prepw_kernel(const float* __restrict__ Wv,
                             const float* __restrict__ Wo,
                             unsigned short* __restrict__ WvT,
                             unsigned short* __restrict__ WeffT) {
    __shared__ float ld[64][65];
    const int b = blockIdx.x;
    const int t = threadIdx.x;
    if (b < 64) {
        // WvT[c][d] = bf16(Wv[d][c]) via 64x64 LDS transpose
        const int d0 = (b & 15) * 64;
        const int c0 = (b >> 4) * 64;
        #pragma unroll
        for (int i = 0; i < 4; ++i) {
            int row  = i * 16 + (t >> 4);
            int col4 = (t & 15) * 4;
            float4 v = *reinterpret_cast<const float4*>(
                Wv + (size_t)(d0 + row) * KVDIM + c0 + col4);
            ld[row][col4 + 0] = v.x; ld[row][col4 + 1] = v.y;
            ld[row][col4 + 2] = v.z; ld[row][col4 + 3] = v.w;
        }
        __syncthreads();
        #pragma unroll
        for (int i = 0; i < 4; ++i) {
            int crow = i * 16 + (t >> 4);
            int dcol = (t & 15) * 4;
            ushort4 o;
            o.x = f2bf(ld[dcol + 0][crow]);
            o.y = f2bf(ld[dcol + 1][crow]);
            o.z = f2bf(ld[dcol + 2][crow]);
            o.w = f2bf(ld[dcol + 3][crow]);
            *reinterpret_cast<ushort4*>(
                WvT + (size_t)(c0 + crow) * DMODEL + d0 + dcol) = o;
        }
    } else {
        // WeffT[m][c] = bf16(fold(Wo)) via 64(m)x64(c) LDS tile
        const int tile = b - 64;
        const int m0 = (tile & 15) * 64;
        const int c0 = (tile >> 4) * 64;
        #pragma unroll
        for (int g = 0; g < 16; ++g) {
            int cl = g * 4 + (t >> 6);
            int ml = t & 63;
            int c  = c0 + cl;
            const float* bp =
                Wo + (size_t)((c >> 6) * 256 + (c & 63)) * DMODEL + m0 + ml;
            float s = bp[0] + bp[(size_t)64 * DMODEL]
                    + bp[(size_t)128 * DMODEL] + bp[(size_t)192 * DMODEL];
            ld[cl][ml] = s;
        }
        __syncthreads();
        const int mrow = t >> 2;
        const int cch  = (t & 3) * 16;
        #pragma unroll
        for (int jj = 0; jj < 4; ++jj) {
            ushort4 o;
            o.x = f2bf(ld[cch + jj * 4 + 0][mrow]);
            o.y = f2bf(ld[cch + jj * 4 + 1][mrow]);
            o.z = f2bf(ld[cch + jj * 4 + 2][mrow]);
            o.w = f2bf(ld[cch + jj * 4 + 3][mrow]);
            *reinterpret_cast<ushort4*>(
                WeffT + (size_t)(m0 + mrow) * KVDIM + c0 + cch + jj * 4) = o;
        }
    }
}

// ---- gemmA: Vb[4096][256] = bf16(x) @ WvT^T ------------------------------
// BM=BN=64, BK=64; 4 waves 2x2, wave tile 32x32 (AM=AN=2).
// A staged as f32 (3 x 16 KB) via global_load_lds; cvt at fragment read.
// LP = 4(A) + 2(B) = 6 loads/wave/stage -> counted vmcnt(6).
__launch_bounds__(256, 2)
__global__ void gemm_xwv(const float* __restrict__ X,
                         const unsigned short* __restrict__ WvT,
                         unsigned short* __restrict__ Vb) {
    __shared__ float Af[3][64 * 64];    // 3 x 16 KB
    __shared__ short Bs[3][64 * 64];    // 3 x  8 KB

    // T1: XCD-chunked swizzle (nwg = 256)
    const int gx  = gridDim.x;                    // 4
    const int bid = blockIdx.y * gx + blockIdx.x;
    const int cpx = (gx * gridDim.y) >> 3;        // 32
    const int swz = (bid & 7) * cpx + (bid >> 3);
    const int brow = (swz / gx) * 64;
    const int bcol = (swz % gx) * 64;

    const int tid  = threadIdx.x;
    const int lane = tid & 63;
    const int w    = tid >> 6;
    const int wr   = w >> 1;
    const int wc   = w & 1;

    const int lr    = lane & 15;
    const int kg    = (lane >> 4) * 8;
    const int arow4 = lane >> 4;          // A staging: row within 4-row chunk
    const int af16  = (lane & 15) * 4;    // A staging: f32 offset (16B/lane)
    const int brow8 = lane >> 3;          // B staging: row within 8-row chunk
    const int bkoff = (lane & 7) * 8;     // B staging: k-elem offset

    f32x4 acc[2][2] = {};

    auto stage = [&](int buf, int kt) {
        #pragma unroll
        for (int i = 0; i < 4; ++i) {
            const int ch = w * 4 + i;                   // 0..15 (4 rows each)
            const float* g =
                X + (size_t)(brow + ch * 4 + arow4) * DMODEL + kt + af16;
            __builtin_amdgcn_global_load_lds(
                (const __attribute__((address_space(1))) void*)g,
                (__attribute__((address_space(3))) void*)(&Af[buf][ch * 256]),
                16, 0, 0);
        }
        #pragma unroll
        for (int i = 0; i < 2; ++i) {
            const int ch = w * 2 + i;                   // 0..7 (8 rows each)
            const unsigned short* g =
                WvT + (size_t)(bcol + ch * 8 + brow8) * DMODEL + kt + bkoff;
            __builtin_amdgcn_global_load_lds(
                (const __attribute__((address_space(1))) void*)g,
                (__attribute__((address_space(3))) void*)(&Bs[buf][ch * 512]),
                16, 0, 0);
        }
    };

    constexpr int nt = DMODEL / 64;       // 16
    stage(0, 0);
    stage(1, 64);
    int bc = 0;
    for (int t = 0; t < nt; ++t) {
        if (t + 1 < nt) asm volatile("s_waitcnt vmcnt(6)" ::: "memory");
        else            asm volatile("s_waitcnt vmcnt(0)" ::: "memory");
        __builtin_amdgcn_s_barrier();

        int bs = bc + 2; if (bs >= 3) bs -= 3;
        if (t + 2 < nt) stage(bs, (t + 2) << 6);

        #pragma unroll
        for (int ks = 0; ks < 2; ++ks) {
            bf16x8 a[2], b[2];
            #pragma unroll
            for (int m = 0; m < 2; ++m) {
                const float* ap =
                    &Af[bc][(wr * 32 + m * 16 + lr) * 64 + ks * 32 + kg];
                float4 f0 = *reinterpret_cast<const float4*>(ap);
                float4 f1 = *reinterpret_cast<const float4*>(ap + 4);
                bf16x8 av;
                av[0] = (short)f2bf(f0.x); av[1] = (short)f2bf(f0.y);
                av[2] = (short)f2bf(f0.z); av[3] = (short)f2bf(f0.w);
                av[4] = (short)f2bf(f1.x); av[5] = (short)f2bf(f1.y);
                av[6] = (short)f2bf(f1.z); av[7] = (short)f2bf(f1.w);
                a[m] = av;
            }
            #pragma unroll
            for (int n = 0; n < 2; ++n)
                b[n] = *reinterpret_cast<const bf16x8*>(
                    &Bs[bc][(wc * 32 + n * 16 + lr) * 64 + ks * 32 + kg]);
            #pragma unroll
            for (int m = 0; m < 2; ++m)
                #pragma unroll
                for (int n = 0; n < 2; ++n)
                    acc[m][n] = __builtin_amdgcn_mfma_f32_16x16x32_bf16(
                        a[m], b[n], acc[m][n], 0, 0, 0);
        }
        bc = (bc == 2) ? 0 : bc + 1;
    }

    // C/D layout: col = lane&15, row = (lane>>4)*4 + reg
    const int rg = (lane >> 4) * 4;
    #pragma unroll
    for (int m = 0; m < 2; ++m)
        #pragma unroll
        for (int n = 0; n < 2; ++n)
            #pragma unroll
            for (int j = 0; j < 4; ++j) {
                const size_t row = brow + wr * 32 + m * 16 + rg + j;
                const size_t col = bcol + wc * 32 + n * 16 + lr;
                Vb[row * KVDIM + col] = f2bf(acc[m][n][j]);
            }
}

// ---- gemmB: out[4096][1024] = Vb @ WeffT^T  (R9 verbatim) ----------------
// BM=128, BN=64, BK=64 + LDS-bounce coalesced f32 epilogue.
__launch_bounds__(256, 2)
__global__ void gemm_vb_weff(const unsigned short* __restrict__ A,
                             const unsigned short* __restrict__ Bt,
                             float* __restrict__ C) {
    constexpr int K = KVDIM;          // 256
    constexpr int N = DMODEL;         // 1024

    __shared__ short As[3][128 * 64];   // 48 KB (reused by epilogue bounce)
    __shared__ short Bs[3][64 * 64];    // 24 KB

    const int gx  = gridDim.x;                    // 16
    const int bid = blockIdx.y * gx + blockIdx.x;
    const int cpx = (gx * gridDim.y) >> 3;        // 64
    const int swz = (bid & 7) * cpx + (bid >> 3);
    const int brow = (swz / gx) * 128;
    const int bcol = (swz % gx) * 64;

    const int tid  = threadIdx.x;
    const int lane = tid & 63;
    const int w    = tid >> 6;
    const int wr   = w >> 1;
    const int wc   = w & 1;

    const int lrow8 = lane >> 3;
    const int lkoff = (lane & 7) * 8;
    const int lr    = lane & 15;
    const int kg    = (lane >> 4) * 8;

    f32x4 acc[4][2] = {};

    auto stage = [&](int buf, int kt) {
        #pragma unroll
        for (int i = 0; i < 4; ++i) {
            const int ch = w * 4 + i;                   // 0..15
            const unsigned short* g =
                A + (size_t)(brow + ch * 8 + lrow8) * K + kt + lkoff;
            __builtin_amdgcn_global_load_lds(
                (const __attribute__((address_space(1))) void*)g,
                (__attribute__((address_space(3))) void*)(&As[buf][ch * 512]),
                16, 0, 0);
        }
        #pragma unroll
        for (int i = 0; i < 2; ++i) {
            const int ch = w * 2 + i;                   // 0..7
            const unsigned short* g =
                Bt + (size_t)(bcol + ch * 8 + lrow8) * K + kt + lkoff;
            __builtin_amdgcn_global_load_lds(
                (const __attribute__((address_space(1))) void*)g,
                (__attribute__((address_space(3))) void*)(&Bs[buf][ch * 512]),
                16, 0, 0);
        }
    };

    constexpr int nt = K / 64;          // 4
    stage(0, 0);
    stage(1, 64);
    int bc = 0;
    for (int t = 0; t < nt; ++t) {
        if (t + 1 < nt) asm volatile("s_waitcnt vmcnt(6)" ::: "memory");
        else            asm volatile("s_waitcnt vmcnt(0)" ::: "memory");
        __builtin_amdgcn_s_barrier();

        int bs = bc + 2; if (bs >= 3) bs -= 3;
        if (t + 2 < nt) stage(bs, (t + 2) << 6);

        #pragma unroll
        for (int ks = 0; ks < 2; ++ks) {
            bf16x8 a[4], b[2];
            #pragma unroll
            for (int m = 0; m < 4; ++m)
                a[m] = *reinterpret_cast<const bf16x8*>(
                    &As[bc][(wr * 64 + m * 16 + lr) * 64 + ks * 32 + kg]);
            #pragma unroll
            for (int n = 0; n < 2; ++n)
                b[n] = *reinterpret_cast<const bf16x8*>(
                    &Bs[bc][(wc * 32 + n * 16 + lr) * 64 + ks * 32 + kg]);
            #pragma unroll
            for (int m = 0; m < 4; ++m)
                #pragma unroll
                for (int n = 0; n < 2; ++n)
                    acc[m][n] = __builtin_amdgcn_mfma_f32_16x16x32_bf16(
                        a[m], b[n], acc[m][n], 0, 0, 0);
        }
        bc = (bc == 2) ? 0 : bc + 1;
    }

    // Epilogue: acc -> LDS [128][65] f32 -> coalesced float4 stores.
    float* Cl = reinterpret_cast<float*>(&As[0][0]);   // 33.3 KB of 48 KB
    __syncthreads();
    const int rg = (lane >> 4) * 4;
    #pragma unroll
    for (int m = 0; m < 4; ++m)
        #pragma unroll
        for (int n = 0; n < 2; ++n)
            #pragma unroll
            for (int j = 0; j < 4; ++j)
                Cl[(wr * 64 + m * 16 + rg + j) * 65
                   + wc * 32 + n * 16 + lr] = acc[m][n][j];
    __syncthreads();
    #pragma unroll
    for (int i = 0; i < 8; ++i) {     // 128x64 f32: 8 float4 per thread
        const int idx = i * 256 + tid;
        const int row = idx >> 4;
        const int c4  = (idx & 15) * 4;
        float4 v;
        v.x = Cl[row * 65 + c4 + 0];
        v.y = Cl[row * 65 + c4 + 1];
        v.z = Cl[row * 65 + c4 + 2];
        v.w = Cl[row * 65 + c4 + 3];
        *reinterpret_cast<float4*>(
            C + (size_t)(brow + row) * N + bcol + c4) = v;
    }
}

extern "C" void kernel_launch(void* const* d_in, const int* in_sizes, int n_in,
                              void* d_out, int out_size, void* d_ws, size_t ws_size,
                              hipStream_t stream) {
    const float* x  = (const float*)d_in[0];   // (4096, 1024)
    const float* Wv = (const float*)d_in[3];   // (1024, 256)
    const float* Wo = (const float*)d_in[4];   // (1024, 1024)
    float* out = (float*)d_out;                // (4096, 1024) f32

    unsigned short* WvT   = (unsigned short*)d_ws;           // 0.5 MB [c][d]
    unsigned short* WeffT = WvT   + (size_t)KVDIM * DMODEL;  // 0.5 MB [m][c]
    unsigned short* Vb    = WeffT + (size_t)DMODEL * KVDIM;  // 2 MB   [r][c]

    prepw_kernel<<<128, 256, 0, stream>>>(Wv, Wo, WvT, WeffT);

    // Vb[r][c] = sum_d bf16(x[r][d]) * WvT[c][d]   (M=4096, N=256, K=1024)
    gemm_xwv<<<dim3(KVDIM / 64, ROWS / 64), 256, 0, stream>>>(x, WvT, Vb);

    // out[r][m] = sum_c Vb[r][c] * WeffT[m][c]     (M=4096, N=1024, K=256)
    gemm_vb_weff<<<dim3(DMODEL / 64, ROWS / 128), 256, 0, stream>>>(
        Vb, WeffT, out);
}